// Round 10
// baseline (432.426 us; speedup 1.0000x reference)
//
#include <hip/hip_runtime.h>
#include <math.h>

#define C 8192
#define D 1024
#define BATCH 1024
#define PM 0.95f
#define PMC 0.05f
// values pre-scaled by 8 before fp8 quant; dot comes out 64x too big.
// epilogue uses 10/64 = 0.15625 (exact in fp32).
#define INVT_SCALED 0.15625f

typedef unsigned char u8;
typedef __attribute__((ext_vector_type(4))) int i32x4;
typedef __attribute__((ext_vector_type(8))) int i32x8;
typedef __attribute__((ext_vector_type(16))) float f32x16;

#define GLOBAL_AS(p) ((const __attribute__((address_space(1))) void*)(p))
#define LDS_AS(p) ((__attribute__((address_space(3))) void*)(p))

// ---------------------------------------------------------------------------
// EMA + fp8 quantize, one wave per class (4 classes/block). Verified r7-r8.
// fp8 layout = ROUND-5-VERIFIED 2048-B tile layout for 32x32x64 f8f6f4:
//   tile (rt=c>>5, kc=k>>6) at (rt*16+kc)*2048; within tile, element (r=c&31,k):
//   sub=(k>>4)&1 (1KB half), h=(k>>5)&1, byte = sub*1024 + (r+32*h)*16 + (k&15).
//   => operand lane L (row r=L&31, half h=L>>5): [lo=tile+L*16 | hi=tile+1024+L*16]
//      gives k (h*32)..(h*32+31) ascending — the f8f6f4 A/B fragment.
__global__ __launch_bounds__(256) void ema_split_kernel(const float* __restrict__ feat,
                                                        const int* __restrict__ labels,
                                                        const float* __restrict__ protos,
                                                        u8* __restrict__ P8,
                                                        float* __restrict__ rowsum,
                                                        float* __restrict__ out) {
    __shared__ int sl[BATCH];
    const int t = threadIdx.x, w = t >> 6, lane = t & 63;
    const int c = blockIdx.x * 4 + w;

    if (blockIdx.x < 32) rowsum[blockIdx.x * 256 + t] = 0.0f;
    if (blockIdx.x == 0 && t == 0) out[0] = 0.0f;

    for (int i = t; i < BATCH; i += 256) sl[i] = labels[i];
    __syncthreads();

    float4 v[4];
    #pragma unroll
    for (int s = 0; s < 4; ++s)
        v[s] = *(const float4*)(protos + (size_t)c * D + s * 256 + lane * 4);

    for (int base = 0; base < BATCH; base += 64) {
        unsigned long long mask = __ballot(sl[base + lane] == c);
        while (mask) {
            const int b = __ffsll((long long)mask) - 1;
            mask &= mask - 1;
            const int idx = base + b;
            float ss = 0.0f;
            #pragma unroll
            for (int s = 0; s < 4; ++s) {
                const float4 f = *(const float4*)(feat + (size_t)idx * D + s * 256 + lane * 4);
                v[s].x = v[s].x * PM + f.x * PMC;
                v[s].y = v[s].y * PM + f.y * PMC;
                v[s].z = v[s].z * PM + f.z * PMC;
                v[s].w = v[s].w * PM + f.w * PMC;
                ss += v[s].x * v[s].x + v[s].y * v[s].y + v[s].z * v[s].z + v[s].w * v[s].w;
            }
            #pragma unroll
            for (int off = 32; off > 0; off >>= 1) ss += __shfl_xor(ss, off);
            const float inv = 1.0f / fmaxf(sqrtf(ss), 1e-12f);
            #pragma unroll
            for (int s = 0; s < 4; ++s) {
                v[s].x *= inv; v[s].y *= inv; v[s].z *= inv; v[s].w *= inv;
            }
        }
    }

    // quantize (x8 pre-scale, RNE) + store 4 consecutive k per uint
    const int rt = c >> 5, r = c & 31;
    u8* ob = P8 + (size_t)rt * 32768;
    #pragma unroll
    for (int s = 0; s < 4; ++s) {
        const int k0 = s * 256 + lane * 4;
        const size_t off = (size_t)(k0 >> 6) * 2048 + ((k0 >> 4) & 1) * 1024
                         + (r + 32 * ((k0 >> 5) & 1)) * 16 + (k0 & 15);
        int p = __builtin_amdgcn_cvt_pk_fp8_f32(v[s].x * 8.0f, v[s].y * 8.0f, 0, false);
        p = __builtin_amdgcn_cvt_pk_fp8_f32(v[s].z * 8.0f, v[s].w * 8.0f, p, true);
        *(unsigned int*)(ob + off) = (unsigned int)p;
    }
}

// ---------------------------------------------------------------------------
// fp8 Gram via mfma_scale_f32_32x32x64_f8f6f4 (scales=1.0, 2x the non-scaled
// fp8 rate, K=64/instr). Round-8 occupancy-first skeleton: 128x128 block tile,
// 256 threads = 4 waves in 2x2, wave tile 64x64 = 2x2 tiles of 32x32
// (64 AGPR acc + ~32 operand VGPRs -> 4 waves/SIMD -> 4 blocks/CU).
// Round-5-verified fragment assembly: two ds_read_b128 per operand
// (lo=tile+lane*16, hi=tile+1024+lane*16) -> shufflevector -> i32x8.
// Double-buffered LDS (16 KB/buf), ONE barrier per BK=64 chunk; staging for
// chunk kc+1 issued right after barrier kc, drained at barrier kc+1.
// Triangle cover bi<=bj over 64 strips of 128 rows (2080 blocks); diag
// blocks mask li>=lj -> rowsum == sum_neg exactly. XCD swizzle: XCD r owns
// strips {r,15-r,16+r,31-r,32+r,47-r,48+r,63-r} (260 blocks each).
__global__ __launch_bounds__(256, 4) void gram8_kernel(const u8* __restrict__ P8,
                                                       float* __restrict__ rowsum) {
    __shared__ u8 lds[2][16384];     // per buf: A tiles 0..3 @ a*2048, B @ 8192+
    __shared__ float rpart[128];
    __shared__ float cpart[128];
    const int t = threadIdx.x, w = t >> 6, lane = t & 63;

    // swizzled block -> (bi, bj), bi <= bj, 128-row strips
    int mm = blockIdx.x >> 3;
    const int r = blockIdx.x & 7;
    int bi = 0;
    #pragma unroll
    for (int s = 0; s < 8; ++s) {
        const int strip = (s & 1) ? ((s >> 1) * 16 + 15 - r) : ((s >> 1) * 16 + r);
        const int n = 64 - strip;
        if (mm < n) { bi = strip; break; }
        mm -= n;
    }
    const int bj = bi + mm;
    const bool diag = (bi == bj);

    if (t < 128) { rpart[t] = 0.0f; cpart[t] = 0.0f; }

    // 4 glds units (1 KB each) per wave: g = gg*4 + w; tile a = (g&7)>>1,
    // half p = g&1; region 0 = A(bi), 1 = B(bj). kc stride = 2048 B.
    const u8* gsrc[4];
    int ldst[4];
    #pragma unroll
    for (int gg = 0; gg < 4; ++gg) {
        const int g = gg * 4 + w;
        const int region = g >> 3;
        const int a = (g & 7) >> 1, p = g & 1;
        const int RT = (region ? bj : bi) * 4 + a;
        gsrc[gg] = P8 + (size_t)RT * 32768 + p * 1024 + lane * 16;
        ldst[gg] = region * 8192 + a * 2048 + p * 1024;
    }

    const int qi = w >> 1, qj = w & 1;
    f32x16 acc[2][2];
    #pragma unroll
    for (int a = 0; a < 2; ++a)
        #pragma unroll
        for (int b = 0; b < 2; ++b)
            #pragma unroll
            for (int e = 0; e < 16; ++e) acc[a][b][e] = 0.0f;

    // prologue: stage chunk 0 into buffer 0
    #pragma unroll
    for (int gg = 0; gg < 4; ++gg)
        __builtin_amdgcn_global_load_lds(GLOBAL_AS(gsrc[gg]),
                                         LDS_AS(&lds[0][ldst[gg]]), 16, 0, 0);

    for (int kc = 0; kc < 16; ++kc) {        // BK = 64
        const int cur = kc & 1;
        __syncthreads();   // drains own glds (chunk kc); buf cur^1 free since barrier kc-1
        if (kc < 15) {
            #pragma unroll
            for (int gg = 0; gg < 4; ++gg)
                __builtin_amdgcn_global_load_lds(GLOBAL_AS(gsrc[gg] + (size_t)(kc + 1) * 2048),
                                                 LDS_AS(&lds[cur ^ 1][ldst[gg]]), 16, 0, 0);
        }
        i32x8 af[2], bf[2];
        #pragma unroll
        for (int ti = 0; ti < 2; ++ti) {
            const int a = qi * 2 + ti;
            const i32x4 lo = *(const i32x4*)&lds[cur][a * 2048 + lane * 16];
            const i32x4 hi = *(const i32x4*)&lds[cur][a * 2048 + 1024 + lane * 16];
            af[ti] = __builtin_shufflevector(lo, hi, 0, 1, 2, 3, 4, 5, 6, 7);
        }
        #pragma unroll
        for (int tj = 0; tj < 2; ++tj) {
            const int b = qj * 2 + tj;
            const i32x4 lo = *(const i32x4*)&lds[cur][8192 + b * 2048 + lane * 16];
            const i32x4 hi = *(const i32x4*)&lds[cur][8192 + b * 2048 + 1024 + lane * 16];
            bf[tj] = __builtin_shufflevector(lo, hi, 0, 1, 2, 3, 4, 5, 6, 7);
        }
        #pragma unroll
        for (int ti = 0; ti < 2; ++ti)
            #pragma unroll
            for (int tj = 0; tj < 2; ++tj)
                acc[ti][tj] = __builtin_amdgcn_mfma_scale_f32_32x32x64_f8f6f4(
                    af[ti], bf[tj], acc[ti][tj], 0, 0,
                    0, 0x7F7F7F7F, 0, 0x7F7F7F7F);   // fp8/fp8, scales = 1.0
    }

    // epilogue: exp(acc*10/64), diag-block triangle mask, row/col partials
    // C layout (32x32): col = lane&31, row = (reg&3) + 8*(reg>>2) + 4*(lane>>5)
    __syncthreads();   // last chunk's frag reads done; rpart/cpart ready
    const int half = lane >> 5, col = lane & 31;
    float csum[2] = {0.0f, 0.0f};
    #pragma unroll
    for (int ti = 0; ti < 2; ++ti) {
        float rs[16];
        #pragma unroll
        for (int reg = 0; reg < 16; ++reg) rs[reg] = 0.0f;
        #pragma unroll
        for (int tj = 0; tj < 2; ++tj) {
            const int lj = qj * 64 + tj * 32 + col;
            #pragma unroll
            for (int reg = 0; reg < 16; ++reg) {
                const int li = qi * 64 + ti * 32 + (reg & 3) + 8 * (reg >> 2) + 4 * half;
                float e = __expf(acc[ti][tj][reg] * INVT_SCALED);
                if (diag && li >= lj) e = 0.0f;      // bi<bj blocks: always li<lj globally
                rs[reg] += e;
                csum[tj] += e;
            }
        }
        #pragma unroll
        for (int reg = 0; reg < 16; ++reg) {
            float v = rs[reg];
            v += __shfl_xor(v, 1); v += __shfl_xor(v, 2); v += __shfl_xor(v, 4);
            v += __shfl_xor(v, 8); v += __shfl_xor(v, 16);
            if (col == 0)
                atomicAdd(&rpart[qi * 64 + ti * 32 + (reg & 3) + 8 * (reg >> 2) + 4 * half], v);
        }
    }
    #pragma unroll
    for (int tj = 0; tj < 2; ++tj) {
        float v = csum[tj];
        v += __shfl_xor(v, 32);
        if (half == 0) atomicAdd(&cpart[qj * 64 + tj * 32 + col], v);
    }
    __syncthreads();
    if (t < 128) atomicAdd(&rowsum[bi * 128 + t], rpart[t]);
    else         atomicAdd(&rowsum[bj * 128 + (t - 128)], cpart[t - 128]);
}

// ---------------------------------------------------------------------------
// rowsum == sum_neg (diag + lower triangle excluded in gram)
__global__ __launch_bounds__(256) void final2_kernel(const float* __restrict__ rowsum,
                                                     float* __restrict__ out) {
    __shared__ float red[4];
    const int t = threadIdx.x;
    const int i = blockIdx.x * 256 + t;
    float v = logf(rowsum[i] * (1.0f / (float)(C - 1)));
    #pragma unroll
    for (int off = 32; off > 0; off >>= 1) v += __shfl_down(v, off);
    if ((t & 63) == 0) red[t >> 6] = v;
    __syncthreads();
    if (t == 0)
        atomicAdd(out, (red[0] + red[1] + red[2] + red[3]) * (1.0f / (float)C));
}

// ---------------------------------------------------------------------------
extern "C" void kernel_launch(void* const* d_in, const int* in_sizes, int n_in,
                              void* d_out, int out_size, void* d_ws, size_t ws_size,
                              hipStream_t stream) {
    const float* feat = (const float*)d_in[0];
    const int* labels = (const int*)d_in[1];
    const float* protos = (const float*)d_in[2];
    float* out = (float*)d_out;
    float* rowsum = (float*)d_ws;               // 32 KB
    u8* P8 = (u8*)((char*)d_ws + 32768);        // 8 MiB packed fp8 protos

    ema_split_kernel<<<C / 4, 256, 0, stream>>>(feat, labels, protos, P8, rowsum, out);
    gram8_kernel<<<2080, 256, 0, stream>>>(P8, rowsum);
    final2_kernel<<<C / 256, 256, 0, stream>>>(rowsum, out);
}

// Round 11
// 275.844 us; speedup vs baseline: 1.5676x; 1.5676x over previous
//
#include <hip/hip_runtime.h>
#include <math.h>

#define C 8192
#define D 1024
#define BATCH 1024
#define PM 0.95f
#define PMC 0.05f
// values pre-scaled by 8 before fp8 quant; dot comes out 64x too big.
// epilogue uses 10/64 = 0.15625 (exact in fp32).
#define INVT_SCALED 0.15625f

typedef unsigned char u8;
typedef __attribute__((ext_vector_type(16))) float f32x16;

#define GLOBAL_AS(p) ((const __attribute__((address_space(1))) void*)(p))
#define LDS_AS(p) ((__attribute__((address_space(3))) void*)(p))

// ---------------------------------------------------------------------------
// EMA + fp8 quantize. 512 blocks x 16 classes (4 per wave, sequential);
// per-class chain/quant logic identical to the round-7/8 verified version.
// Round-8 P8 layout (512-B k-units for 32x32x16 fp8 MFMA):
//   element (row c, k) -> P8[(c>>5)*32768 + (k>>4)*512 + ((k>>3)&1)*256 + (c&31)*8 + (k&7)]
// Also zeroes rowsum (blocks 0..31) and the gram completion counter (block 0).
__global__ __launch_bounds__(256) void ema_split_kernel(const float* __restrict__ feat,
                                                        const int* __restrict__ labels,
                                                        const float* __restrict__ protos,
                                                        u8* __restrict__ P8,
                                                        float* __restrict__ rowsum,
                                                        int* __restrict__ done) {
    __shared__ int sl[BATCH];
    const int t = threadIdx.x, w = t >> 6, lane = t & 63;

    if (blockIdx.x < 32) rowsum[blockIdx.x * 256 + t] = 0.0f;
    if (blockIdx.x == 0 && t == 0) *done = 0;

    for (int i = t; i < BATCH; i += 256) sl[i] = labels[i];
    __syncthreads();

    for (int ci = 0; ci < 4; ++ci) {
        const int c = blockIdx.x * 16 + w * 4 + ci;

        float4 v[4];
        #pragma unroll
        for (int s = 0; s < 4; ++s)
            v[s] = *(const float4*)(protos + (size_t)c * D + s * 256 + lane * 4);

        for (int base = 0; base < BATCH; base += 64) {
            unsigned long long mask = __ballot(sl[base + lane] == c);
            while (mask) {
                const int b = __ffsll((long long)mask) - 1;
                mask &= mask - 1;
                const int idx = base + b;
                float ss = 0.0f;
                #pragma unroll
                for (int s = 0; s < 4; ++s) {
                    const float4 f = *(const float4*)(feat + (size_t)idx * D + s * 256 + lane * 4);
                    v[s].x = v[s].x * PM + f.x * PMC;
                    v[s].y = v[s].y * PM + f.y * PMC;
                    v[s].z = v[s].z * PM + f.z * PMC;
                    v[s].w = v[s].w * PM + f.w * PMC;
                    ss += v[s].x * v[s].x + v[s].y * v[s].y + v[s].z * v[s].z + v[s].w * v[s].w;
                }
                #pragma unroll
                for (int off = 32; off > 0; off >>= 1) ss += __shfl_xor(ss, off);
                const float inv = 1.0f / fmaxf(sqrtf(ss), 1e-12f);
                #pragma unroll
                for (int s = 0; s < 4; ++s) {
                    v[s].x *= inv; v[s].y *= inv; v[s].z *= inv; v[s].w *= inv;
                }
            }
        }

        // quantize (x8 pre-scale, RNE) + store 4 consecutive k per uint
        u8* ob = P8 + (size_t)(c >> 5) * 32768 + (c & 31) * 8;
        #pragma unroll
        for (int s = 0; s < 4; ++s) {
            const int k0 = s * 256 + lane * 4;
            const size_t off = (size_t)(k0 >> 4) * 512 + ((k0 >> 3) & 1) * 256 + (k0 & 7);
            int p = __builtin_amdgcn_cvt_pk_fp8_f32(v[s].x * 8.0f, v[s].y * 8.0f, 0, false);
            p = __builtin_amdgcn_cvt_pk_fp8_f32(v[s].z * 8.0f, v[s].w * 8.0f, p, true);
            *(unsigned int*)(ob + off) = (unsigned int)p;
        }
    }
}

// ---------------------------------------------------------------------------
// fp8 Gram, mfma_f32_32x32x16_fp8_fp8 — ROUND-8 VERIFIED STRUCTURE (77 us,
// no spill): 128x128 block tile, 256 threads = 4 waves in 2x2, wave tile
// 64x64 = 2x2 tiles of 32x32 (64 AGPR acc, long operands via ds_read_b64)
// -> 4 waves/SIMD -> 4 blocks/CU. Double-buffered LDS (16 KB/buf), ONE
// barrier per BK=64 chunk. Triangle cover bi<=bj over 64 strips (2080
// blocks); diag blocks mask li>=lj -> rowsum == sum_neg exactly. XCD
// swizzle: XCD r owns strips {r,15-r,16+r,31-r,...} (260 blocks each).
// NEW: final log-mean fused via completion counter — last block re-reads
// rowsum with coherent atomicAdd(p, 0.0f) and writes out[0] directly.
__global__ __launch_bounds__(256, 4) void gram8_kernel(const u8* __restrict__ P8,
                                                       float* __restrict__ rowsum,
                                                       int* __restrict__ done,
                                                       float* __restrict__ out) {
    __shared__ u8 lds[2][16384];     // per buf: A units @ a*2048+p*1024, B @ 8192+
    __shared__ float rpart[128];
    __shared__ float cpart[128];
    __shared__ int ticket_s;
    const int t = threadIdx.x, w = t >> 6, lane = t & 63;

    // swizzled block -> (bi, bj), bi <= bj, 128-row strips
    int mm = blockIdx.x >> 3;
    const int r = blockIdx.x & 7;
    int bi = 0;
    #pragma unroll
    for (int s = 0; s < 8; ++s) {
        const int strip = (s & 1) ? ((s >> 1) * 16 + 15 - r) : ((s >> 1) * 16 + r);
        const int n = 64 - strip;
        if (mm < n) { bi = strip; break; }
        mm -= n;
    }
    const int bj = bi + mm;
    const bool diag = (bi == bj);

    if (t < 128) { rpart[t] = 0.0f; cpart[t] = 0.0f; }

    // 4 glds units (1 KB each) per wave: g = gg*4 + w; tile a = (g&7)>>1,
    // half p = g&1; region 0 = A(bi), 1 = B(bj). kc stride = 2048 B.
    const u8* gsrc[4];
    int ldst[4];
    #pragma unroll
    for (int gg = 0; gg < 4; ++gg) {
        const int g = gg * 4 + w;
        const int region = g >> 3;
        const int a = (g & 7) >> 1, p = g & 1;
        const int RT = (region ? bj : bi) * 4 + a;
        gsrc[gg] = P8 + (size_t)RT * 32768 + p * 1024 + lane * 16;
        ldst[gg] = region * 8192 + a * 2048 + p * 1024;
    }

    const int qi = w >> 1, qj = w & 1;
    f32x16 acc[2][2];
    #pragma unroll
    for (int a = 0; a < 2; ++a)
        #pragma unroll
        for (int b = 0; b < 2; ++b)
            #pragma unroll
            for (int e = 0; e < 16; ++e) acc[a][b][e] = 0.0f;

    // prologue: stage chunk 0 into buffer 0
    #pragma unroll
    for (int gg = 0; gg < 4; ++gg)
        __builtin_amdgcn_global_load_lds(GLOBAL_AS(gsrc[gg]),
                                         LDS_AS(&lds[0][ldst[gg]]), 16, 0, 0);

    for (int kc = 0; kc < 16; ++kc) {        // BK = 64
        const int cur = kc & 1;
        __syncthreads();   // drains own glds (chunk kc); buf cur^1 free since barrier kc-1
        if (kc < 15) {
            #pragma unroll
            for (int gg = 0; gg < 4; ++gg)
                __builtin_amdgcn_global_load_lds(GLOBAL_AS(gsrc[gg] + (size_t)(kc + 1) * 2048),
                                                 LDS_AS(&lds[cur ^ 1][ldst[gg]]), 16, 0, 0);
        }
        #pragma unroll
        for (int kk = 0; kk < 4; ++kk) {     // 4 K-steps of K=16
            long af[2], bf[2];
            #pragma unroll
            for (int ti = 0; ti < 2; ++ti)
                af[ti] = *(const long*)&lds[cur][((qi * 2 + ti) * 4 + kk) * 512 + lane * 8];
            #pragma unroll
            for (int tj = 0; tj < 2; ++tj)
                bf[tj] = *(const long*)&lds[cur][8192 + ((qj * 2 + tj) * 4 + kk) * 512 + lane * 8];
            #pragma unroll
            for (int ti = 0; ti < 2; ++ti)
                #pragma unroll
                for (int tj = 0; tj < 2; ++tj)
                    acc[ti][tj] = __builtin_amdgcn_mfma_f32_32x32x16_fp8_fp8(
                        af[ti], bf[tj], acc[ti][tj], 0, 0, 0);
        }
    }

    // epilogue: exp(acc*10/64), diag-block triangle mask, row/col partials
    // C layout (32x32): col = lane&31, row = (reg&3) + 8*(reg>>2) + 4*(lane>>5)
    __syncthreads();   // last chunk's frag reads done; rpart/cpart ready
    const int half = lane >> 5, col = lane & 31;
    float csum[2] = {0.0f, 0.0f};
    #pragma unroll
    for (int ti = 0; ti < 2; ++ti) {
        float rs[16];
        #pragma unroll
        for (int reg = 0; reg < 16; ++reg) rs[reg] = 0.0f;
        #pragma unroll
        for (int tj = 0; tj < 2; ++tj) {
            const int lj = qj * 64 + tj * 32 + col;
            #pragma unroll
            for (int reg = 0; reg < 16; ++reg) {
                const int li = qi * 64 + ti * 32 + (reg & 3) + 8 * (reg >> 2) + 4 * half;
                float e = __expf(acc[ti][tj][reg] * INVT_SCALED);
                if (diag && li >= lj) e = 0.0f;      // bi<bj blocks: always li<lj globally
                rs[reg] += e;
                csum[tj] += e;
            }
        }
        #pragma unroll
        for (int reg = 0; reg < 16; ++reg) {
            float v = rs[reg];
            v += __shfl_xor(v, 1); v += __shfl_xor(v, 2); v += __shfl_xor(v, 4);
            v += __shfl_xor(v, 8); v += __shfl_xor(v, 16);
            if (col == 0)
                atomicAdd(&rpart[qi * 64 + ti * 32 + (reg & 3) + 8 * (reg >> 2) + 4 * half], v);
        }
    }
    #pragma unroll
    for (int tj = 0; tj < 2; ++tj) {
        float v = csum[tj];
        v += __shfl_xor(v, 32);
        if (half == 0) atomicAdd(&cpart[qj * 64 + tj * 32 + col], v);
    }
    __syncthreads();
    if (t < 128) atomicAdd(&rowsum[bi * 128 + t], rpart[t]);
    else         atomicAdd(&rowsum[bj * 128 + (t - 128)], cpart[t - 128]);

    // ---- fused final: last completing block computes the loss ----
    __threadfence();                       // release rowsum updates (device scope)
    if (t == 0) ticket_s = atomicAdd(done, 1);
    __syncthreads();
    if (ticket_s == 2079) {
        float lsum = 0.0f;
        for (int i = t; i < C; i += 256) {
            const float rv = atomicAdd(&rowsum[i], 0.0f);   // coherent cross-XCD read
            lsum += logf(rv * (1.0f / (float)(C - 1)));
        }
        #pragma unroll
        for (int off = 32; off > 0; off >>= 1) lsum += __shfl_xor(lsum, off);
        if (lane == 0) rpart[w] = lsum;    // rpart reused as scratch
        __syncthreads();
        if (t == 0)
            out[0] = (rpart[0] + rpart[1] + rpart[2] + rpart[3]) * (1.0f / (float)C);
    }
}

// ---------------------------------------------------------------------------
extern "C" void kernel_launch(void* const* d_in, const int* in_sizes, int n_in,
                              void* d_out, int out_size, void* d_ws, size_t ws_size,
                              hipStream_t stream) {
    const float* feat = (const float*)d_in[0];
    const int* labels = (const int*)d_in[1];
    const float* protos = (const float*)d_in[2];
    float* out = (float*)d_out;
    float* rowsum = (float*)d_ws;               // 32 KB
    int* done = (int*)((char*)d_ws + 32768);    // 4 B completion counter
    u8* P8 = (u8*)((char*)d_ws + 65536);        // 8 MiB packed fp8 protos

    ema_split_kernel<<<512, 256, 0, stream>>>(feat, labels, protos, P8, rowsum, done);
    gram8_kernel<<<2080, 256, 0, stream>>>(P8, rowsum, done, out);
}

// Round 12
// 163.024 us; speedup vs baseline: 2.6525x; 1.6920x over previous
//
#include <hip/hip_runtime.h>
#include <math.h>

#define C 8192
#define D 1024
#define BATCH 1024
#define PM 0.95f
#define PMC 0.05f
// values pre-scaled by 8 before fp8 quant; dot comes out 64x too big.
// epilogue uses 10/64 = 0.15625 (exact in fp32).
#define INVT_SCALED 0.15625f

typedef unsigned char u8;
typedef __attribute__((ext_vector_type(16))) float f32x16;

#define GLOBAL_AS(p) ((const __attribute__((address_space(1))) void*)(p))
#define LDS_AS(p) ((__attribute__((address_space(3))) void*)(p))

// ---------------------------------------------------------------------------
// EMA + fp8 quantize, one wave per class (4 classes/block, 2048 blocks).
// Verified rounds 7-8. fp8 layout (512-B k-units for 32x32x16 fp8 MFMA):
//   element (row c, k) -> P8[(c>>5)*32768 + (k>>4)*512 + ((k>>3)&1)*256 + (c&31)*8 + (k&7)]
__global__ __launch_bounds__(256) void ema_split_kernel(const float* __restrict__ feat,
                                                        const int* __restrict__ labels,
                                                        const float* __restrict__ protos,
                                                        u8* __restrict__ P8,
                                                        float* __restrict__ rowsum,
                                                        float* __restrict__ out) {
    __shared__ int sl[BATCH];
    const int t = threadIdx.x, w = t >> 6, lane = t & 63;
    const int c = blockIdx.x * 4 + w;

    if (blockIdx.x < 32) rowsum[blockIdx.x * 256 + t] = 0.0f;
    if (blockIdx.x == 0 && t == 0) out[0] = 0.0f;

    for (int i = t; i < BATCH; i += 256) sl[i] = labels[i];
    __syncthreads();

    float4 v[4];
    #pragma unroll
    for (int s = 0; s < 4; ++s)
        v[s] = *(const float4*)(protos + (size_t)c * D + s * 256 + lane * 4);

    for (int base = 0; base < BATCH; base += 64) {
        unsigned long long mask = __ballot(sl[base + lane] == c);
        while (mask) {
            const int b = __ffsll((long long)mask) - 1;
            mask &= mask - 1;
            const int idx = base + b;
            float ss = 0.0f;
            #pragma unroll
            for (int s = 0; s < 4; ++s) {
                const float4 f = *(const float4*)(feat + (size_t)idx * D + s * 256 + lane * 4);
                v[s].x = v[s].x * PM + f.x * PMC;
                v[s].y = v[s].y * PM + f.y * PMC;
                v[s].z = v[s].z * PM + f.z * PMC;
                v[s].w = v[s].w * PM + f.w * PMC;
                ss += v[s].x * v[s].x + v[s].y * v[s].y + v[s].z * v[s].z + v[s].w * v[s].w;
            }
            #pragma unroll
            for (int off = 32; off > 0; off >>= 1) ss += __shfl_xor(ss, off);
            const float inv = 1.0f / fmaxf(sqrtf(ss), 1e-12f);
            #pragma unroll
            for (int s = 0; s < 4; ++s) {
                v[s].x *= inv; v[s].y *= inv; v[s].z *= inv; v[s].w *= inv;
            }
        }
    }

    u8* ob = P8 + (size_t)(c >> 5) * 32768 + (c & 31) * 8;
    #pragma unroll
    for (int s = 0; s < 4; ++s) {
        const int k0 = s * 256 + lane * 4;
        const size_t off = (size_t)(k0 >> 4) * 512 + ((k0 >> 3) & 1) * 256 + (k0 & 7);
        int p = __builtin_amdgcn_cvt_pk_fp8_f32(v[s].x * 8.0f, v[s].y * 8.0f, 0, false);
        p = __builtin_amdgcn_cvt_pk_fp8_f32(v[s].z * 8.0f, v[s].w * 8.0f, p, true);
        *(unsigned int*)(ob + off) = (unsigned int)p;
    }
}

// ---------------------------------------------------------------------------
// fp8 Gram, mfma_f32_32x32x16_fp8_fp8 on the r8 skeleton (128x128 block tile,
// 4 waves 2x2, wave tile 64x64, 64 AGPR acc, 4 blocks/CU) with an
// AITER-style K-loop: triple-buffered BK=32 chunks (3 x 8 KB LDS) and raw
// s_barrier preceded by PARTIAL "s_waitcnt vmcnt(2)" — each wave waits only
// for its own chunk-kc glds (oldest 2), leaving chunk kc+1's 2 loads in
// flight across the barrier (no vmcnt(0) drain; every wave certifies its own
// staging, so post-barrier the whole chunk is LDS-resident). glds for kc+2
// issued AFTER the barrier -> WAR-safe on the recycled buffer (all waves
// finished compute kc-1). Triangle cover bi<=bj, 2080 blocks; diag blocks
// mask li>=lj -> rowsum == sum_neg. XCD swizzle: 260 blocks/XCD.
__global__ __launch_bounds__(256, 4) void gram8_kernel(const u8* __restrict__ P8,
                                                       float* __restrict__ rowsum) {
    __shared__ u8 lds[3][8192];      // per buf: A tiles 0..3 @ a*1024, B @ 4096+
    __shared__ float rpart[128];
    __shared__ float cpart[128];
    const int t = threadIdx.x, w = t >> 6, lane = t & 63;

    // swizzled block -> (bi, bj), bi <= bj, 128-row strips
    int mm = blockIdx.x >> 3;
    const int r = blockIdx.x & 7;
    int bi = 0;
    #pragma unroll
    for (int s = 0; s < 8; ++s) {
        const int strip = (s & 1) ? ((s >> 1) * 16 + 15 - r) : ((s >> 1) * 16 + r);
        const int n = 64 - strip;
        if (mm < n) { bi = strip; break; }
        mm -= n;
    }
    const int bj = bi + mm;
    const bool diag = (bi == bj);

    if (t < 128) { rpart[t] = 0.0f; cpart[t] = 0.0f; }

    // per-wave staging: 2 glds x 1 KB per chunk (A tile w, B tile w)
    const u8* gsrcA = P8 + (size_t)(bi * 4 + w) * 32768 + lane * 16;
    const u8* gsrcB = P8 + (size_t)(bj * 4 + w) * 32768 + lane * 16;
    const int ldsA = w * 1024, ldsB = 4096 + w * 1024;

    const int qi = w >> 1, qj = w & 1;
    f32x16 acc[2][2];
    #pragma unroll
    for (int a = 0; a < 2; ++a)
        #pragma unroll
        for (int b = 0; b < 2; ++b)
            #pragma unroll
            for (int e = 0; e < 16; ++e) acc[a][b][e] = 0.0f;

    // prologue: stage chunks 0 (buf 0) and 1 (buf 1); 4 glds outstanding/wave
    __builtin_amdgcn_global_load_lds(GLOBAL_AS(gsrcA), LDS_AS(&lds[0][ldsA]), 16, 0, 0);
    __builtin_amdgcn_global_load_lds(GLOBAL_AS(gsrcB), LDS_AS(&lds[0][ldsB]), 16, 0, 0);
    __builtin_amdgcn_global_load_lds(GLOBAL_AS(gsrcA + 1024), LDS_AS(&lds[1][ldsA]), 16, 0, 0);
    __builtin_amdgcn_global_load_lds(GLOBAL_AS(gsrcB + 1024), LDS_AS(&lds[1][ldsB]), 16, 0, 0);

    int cb = 0, sb = 2;                      // compute buffer, stage buffer
    for (int kc = 0; kc < 31; ++kc) {        // BK = 32, 32 chunks, last peeled
        // own chunk-kc glds (oldest 2) complete; kc+1's stay in flight
        asm volatile("s_waitcnt vmcnt(2)" ::: "memory");
        __builtin_amdgcn_s_barrier();
        if (kc < 30) {
            __builtin_amdgcn_global_load_lds(GLOBAL_AS(gsrcA + (size_t)(kc + 2) * 1024),
                                             LDS_AS(&lds[sb][ldsA]), 16, 0, 0);
            __builtin_amdgcn_global_load_lds(GLOBAL_AS(gsrcB + (size_t)(kc + 2) * 1024),
                                             LDS_AS(&lds[sb][ldsB]), 16, 0, 0);
        }
        #pragma unroll
        for (int kk = 0; kk < 2; ++kk) {     // 2 K-steps of K=16
            long af[2], bf[2];
            #pragma unroll
            for (int ti = 0; ti < 2; ++ti)
                af[ti] = *(const long*)&lds[cb][(qi * 2 + ti) * 1024 + kk * 512 + lane * 8];
            #pragma unroll
            for (int tj = 0; tj < 2; ++tj)
                bf[tj] = *(const long*)&lds[cb][4096 + (qj * 2 + tj) * 1024 + kk * 512 + lane * 8];
            #pragma unroll
            for (int ti = 0; ti < 2; ++ti)
                #pragma unroll
                for (int tj = 0; tj < 2; ++tj)
                    acc[ti][tj] = __builtin_amdgcn_mfma_f32_32x32x16_fp8_fp8(
                        af[ti], bf[tj], acc[ti][tj], 0, 0, 0);
        }
        cb = (cb == 2) ? 0 : cb + 1;
        sb = (sb == 2) ? 0 : sb + 1;
    }
    // peeled last chunk (kc = 31): only its own 2 loads outstanding
    asm volatile("s_waitcnt vmcnt(0)" ::: "memory");
    __builtin_amdgcn_s_barrier();
    #pragma unroll
    for (int kk = 0; kk < 2; ++kk) {
        long af[2], bf[2];
        #pragma unroll
        for (int ti = 0; ti < 2; ++ti)
            af[ti] = *(const long*)&lds[cb][(qi * 2 + ti) * 1024 + kk * 512 + lane * 8];
        #pragma unroll
        for (int tj = 0; tj < 2; ++tj)
            bf[tj] = *(const long*)&lds[cb][4096 + (qj * 2 + tj) * 1024 + kk * 512 + lane * 8];
        #pragma unroll
        for (int ti = 0; ti < 2; ++ti)
            #pragma unroll
            for (int tj = 0; tj < 2; ++tj)
                acc[ti][tj] = __builtin_amdgcn_mfma_f32_32x32x16_fp8_fp8(
                    af[ti], bf[tj], acc[ti][tj], 0, 0, 0);
    }

    // epilogue: exp(acc*10/64), diag-block triangle mask, row/col partials
    // C layout (32x32): col = lane&31, row = (reg&3) + 8*(reg>>2) + 4*(lane>>5)
    __syncthreads();   // rpart/cpart zero-init visible; all frag reads done
    const int half = lane >> 5, col = lane & 31;
    float csum[2] = {0.0f, 0.0f};
    #pragma unroll
    for (int ti = 0; ti < 2; ++ti) {
        float rs[16];
        #pragma unroll
        for (int reg = 0; reg < 16; ++reg) rs[reg] = 0.0f;
        #pragma unroll
        for (int tj = 0; tj < 2; ++tj) {
            const int lj = qj * 64 + tj * 32 + col;
            #pragma unroll
            for (int reg = 0; reg < 16; ++reg) {
                const int li = qi * 64 + ti * 32 + (reg & 3) + 8 * (reg >> 2) + 4 * half;
                float e = __expf(acc[ti][tj][reg] * INVT_SCALED);
                if (diag && li >= lj) e = 0.0f;      // bi<bj blocks: always li<lj globally
                rs[reg] += e;
                csum[tj] += e;
            }
        }
        #pragma unroll
        for (int reg = 0; reg < 16; ++reg) {
            float v = rs[reg];
            v += __shfl_xor(v, 1); v += __shfl_xor(v, 2); v += __shfl_xor(v, 4);
            v += __shfl_xor(v, 8); v += __shfl_xor(v, 16);
            if (col == 0)
                atomicAdd(&rpart[qi * 64 + ti * 32 + (reg & 3) + 8 * (reg >> 2) + 4 * half], v);
        }
    }
    #pragma unroll
    for (int tj = 0; tj < 2; ++tj) {
        float v = csum[tj];
        v += __shfl_xor(v, 32);
        if (half == 0) atomicAdd(&cpart[qj * 64 + tj * 32 + col], v);
    }
    __syncthreads();
    if (t < 128) atomicAdd(&rowsum[bi * 128 + t], rpart[t]);
    else         atomicAdd(&rowsum[bj * 128 + (t - 128)], cpart[t - 128]);
}

// ---------------------------------------------------------------------------
// rowsum == sum_neg (diag + lower triangle excluded in gram)
__global__ __launch_bounds__(256) void final2_kernel(const float* __restrict__ rowsum,
                                                     float* __restrict__ out) {
    __shared__ float red[4];
    const int t = threadIdx.x;
    const int i = blockIdx.x * 256 + t;
    float v = logf(rowsum[i] * (1.0f / (float)(C - 1)));
    #pragma unroll
    for (int off = 32; off > 0; off >>= 1) v += __shfl_down(v, off);
    if ((t & 63) == 0) red[t >> 6] = v;
    __syncthreads();
    if (t == 0)
        atomicAdd(out, (red[0] + red[1] + red[2] + red[3]) * (1.0f / (float)C));
}

// ---------------------------------------------------------------------------
extern "C" void kernel_launch(void* const* d_in, const int* in_sizes, int n_in,
                              void* d_out, int out_size, void* d_ws, size_t ws_size,
                              hipStream_t stream) {
    const float* feat = (const float*)d_in[0];
    const int* labels = (const int*)d_in[1];
    const float* protos = (const float*)d_in[2];
    float* out = (float*)d_out;
    float* rowsum = (float*)d_ws;               // 32 KB
    u8* P8 = (u8*)((char*)d_ws + 32768);        // 8 MiB packed fp8 protos

    ema_split_kernel<<<C / 4, 256, 0, stream>>>(feat, labels, protos, P8, rowsum, out);
    gram8_kernel<<<2080, 256, 0, stream>>>(P8, rowsum);
    final2_kernel<<<C / 256, 256, 0, stream>>>(rowsum, out);
}

// Round 13
// 155.212 us; speedup vs baseline: 2.7860x; 1.0503x over previous
//
#include <hip/hip_runtime.h>
#include <math.h>

#define C 8192
#define D 1024
#define BATCH 1024
#define PM 0.95f
#define PMC 0.05f
// values pre-scaled by 8 before fp8 quant; dot comes out 64x too big.
// epilogue uses 10/64 = 0.15625 (exact in fp32).
#define INVT_SCALED 0.15625f

typedef unsigned char u8;
typedef __attribute__((ext_vector_type(16))) float f32x16;

#define GLOBAL_AS(p) ((const __attribute__((address_space(1))) void*)(p))
#define LDS_AS(p) ((__attribute__((address_space(3))) void*)(p))

// ---------------------------------------------------------------------------
// EMA + fp8 quantize, one wave per class (4 classes/block, 2048 blocks).
// Verified rounds 7-12. fp8 layout (512-B k-units for 32x32x16 fp8 MFMA):
//   element (row c, k) -> P8[(c>>5)*32768 + (k>>4)*512 + ((k>>3)&1)*256 + (c&31)*8 + (k&7)]
__global__ __launch_bounds__(256) void ema_split_kernel(const float* __restrict__ feat,
                                                        const int* __restrict__ labels,
                                                        const float* __restrict__ protos,
                                                        u8* __restrict__ P8,
                                                        float* __restrict__ rowsum,
                                                        float* __restrict__ out) {
    __shared__ int sl[BATCH];
    const int t = threadIdx.x, w = t >> 6, lane = t & 63;
    const int c = blockIdx.x * 4 + w;

    if (blockIdx.x < 32) rowsum[blockIdx.x * 256 + t] = 0.0f;
    if (blockIdx.x == 0 && t == 0) out[0] = 0.0f;

    for (int i = t; i < BATCH; i += 256) sl[i] = labels[i];
    __syncthreads();

    float4 v[4];
    #pragma unroll
    for (int s = 0; s < 4; ++s)
        v[s] = *(const float4*)(protos + (size_t)c * D + s * 256 + lane * 4);

    for (int base = 0; base < BATCH; base += 64) {
        unsigned long long mask = __ballot(sl[base + lane] == c);
        while (mask) {
            const int b = __ffsll((long long)mask) - 1;
            mask &= mask - 1;
            const int idx = base + b;
            float ss = 0.0f;
            #pragma unroll
            for (int s = 0; s < 4; ++s) {
                const float4 f = *(const float4*)(feat + (size_t)idx * D + s * 256 + lane * 4);
                v[s].x = v[s].x * PM + f.x * PMC;
                v[s].y = v[s].y * PM + f.y * PMC;
                v[s].z = v[s].z * PM + f.z * PMC;
                v[s].w = v[s].w * PM + f.w * PMC;
                ss += v[s].x * v[s].x + v[s].y * v[s].y + v[s].z * v[s].z + v[s].w * v[s].w;
            }
            #pragma unroll
            for (int off = 32; off > 0; off >>= 1) ss += __shfl_xor(ss, off);
            const float inv = 1.0f / fmaxf(sqrtf(ss), 1e-12f);
            #pragma unroll
            for (int s = 0; s < 4; ++s) {
                v[s].x *= inv; v[s].y *= inv; v[s].z *= inv; v[s].w *= inv;
            }
        }
    }

    u8* ob = P8 + (size_t)(c >> 5) * 32768 + (c & 31) * 8;
    #pragma unroll
    for (int s = 0; s < 4; ++s) {
        const int k0 = s * 256 + lane * 4;
        const size_t off = (size_t)(k0 >> 4) * 512 + ((k0 >> 3) & 1) * 256 + (k0 & 7);
        int p = __builtin_amdgcn_cvt_pk_fp8_f32(v[s].x * 8.0f, v[s].y * 8.0f, 0, false);
        p = __builtin_amdgcn_cvt_pk_fp8_f32(v[s].z * 8.0f, v[s].w * 8.0f, p, true);
        *(unsigned int*)(ob + off) = (unsigned int)p;
    }
}

// ---------------------------------------------------------------------------
// fp8 Gram, mfma_f32_32x32x16_fp8_fp8, r8 tile geometry (128x128 block,
// 4 waves 2x2, wave tile 64x64, 64 AGPR acc, 4 blocks/CU) with a DEEP
// 5-buffer pipeline (40 KB LDS = exactly 160 KB/CU at 4 blocks):
// buffers hold chunks kc..kc+4 (BK=32, 1 KB A + 1 KB B per wave per chunk).
// Period kc: s_waitcnt vmcnt(6) [8 outstanding, waits ONLY the oldest 2 =
// chunk kc, staged 4 periods ago -> ~4 periods of latency cover] ->
// s_barrier -> stage chunk kc+4 into buf (kc+4)%5 (holds chunk kc-1; freed
// by this barrier - WAR exact) -> compute kc. Tail peeled vmcnt(4)/(2)/(0).
// rpart/cpart live in the dead LDS buffers after the K-loop.
// Triangle cover bi<=bj (2080 blocks); diag blocks mask li>=lj ->
// rowsum == sum_neg. XCD swizzle: 260 blocks/XCD.
__global__ __launch_bounds__(256, 4) void gram8_kernel(const u8* __restrict__ P8,
                                                       float* __restrict__ rowsum) {
    __shared__ u8 lds[5][8192];      // per buf: A tiles 0..3 @ a*1024, B @ 4096+
    const int t = threadIdx.x, w = t >> 6, lane = t & 63;

    // swizzled block -> (bi, bj), bi <= bj, 128-row strips
    int mm = blockIdx.x >> 3;
    const int r = blockIdx.x & 7;
    int bi = 0;
    #pragma unroll
    for (int s = 0; s < 8; ++s) {
        const int strip = (s & 1) ? ((s >> 1) * 16 + 15 - r) : ((s >> 1) * 16 + r);
        const int n = 64 - strip;
        if (mm < n) { bi = strip; break; }
        mm -= n;
    }
    const int bj = bi + mm;
    const bool diag = (bi == bj);

    // per-wave staging: 2 glds x 1 KB per chunk (A tile w, B tile w)
    const u8* gsrcA = P8 + (size_t)(bi * 4 + w) * 32768 + lane * 16;
    const u8* gsrcB = P8 + (size_t)(bj * 4 + w) * 32768 + lane * 16;
    const int ldsA = w * 1024, ldsB = 4096 + w * 1024;

    const int qi = w >> 1, qj = w & 1;
    f32x16 acc[2][2];
    #pragma unroll
    for (int a = 0; a < 2; ++a)
        #pragma unroll
        for (int b = 0; b < 2; ++b)
            #pragma unroll
            for (int e = 0; e < 16; ++e) acc[a][b][e] = 0.0f;

    auto compute = [&](int buf) {
        #pragma unroll
        for (int kk = 0; kk < 2; ++kk) {     // 2 K-steps of K=16
            long af[2], bf[2];
            #pragma unroll
            for (int ti = 0; ti < 2; ++ti)
                af[ti] = *(const long*)&lds[buf][(qi * 2 + ti) * 1024 + kk * 512 + lane * 8];
            #pragma unroll
            for (int tj = 0; tj < 2; ++tj)
                bf[tj] = *(const long*)&lds[buf][4096 + (qj * 2 + tj) * 1024 + kk * 512 + lane * 8];
            #pragma unroll
            for (int ti = 0; ti < 2; ++ti)
                #pragma unroll
                for (int tj = 0; tj < 2; ++tj)
                    acc[ti][tj] = __builtin_amdgcn_mfma_f32_32x32x16_fp8_fp8(
                        af[ti], bf[tj], acc[ti][tj], 0, 0, 0);
        }
    };

    // prologue: stage chunks 0..3 into bufs 0..3 (8 glds outstanding/wave)
    #pragma unroll
    for (int cc = 0; cc < 4; ++cc) {
        __builtin_amdgcn_global_load_lds(GLOBAL_AS(gsrcA + (size_t)cc * 1024),
                                         LDS_AS(&lds[cc][ldsA]), 16, 0, 0);
        __builtin_amdgcn_global_load_lds(GLOBAL_AS(gsrcB + (size_t)cc * 1024),
                                         LDS_AS(&lds[cc][ldsB]), 16, 0, 0);
    }

    int cb = 0;                              // buffer of chunk kc (kc % 5)
    for (int kc = 0; kc < 29; ++kc) {        // chunks 0..28; tail peeled
        asm volatile("s_waitcnt vmcnt(6)" ::: "memory");   // oldest 2 (chunk kc) done
        __builtin_amdgcn_s_barrier();
        if (kc < 28) {                       // stage chunk kc+4 into buf (kc+4)%5
            const int sb = (cb == 0) ? 4 : cb - 1;
            __builtin_amdgcn_global_load_lds(GLOBAL_AS(gsrcA + (size_t)(kc + 4) * 1024),
                                             LDS_AS(&lds[sb][ldsA]), 16, 0, 0);
            __builtin_amdgcn_global_load_lds(GLOBAL_AS(gsrcB + (size_t)(kc + 4) * 1024),
                                             LDS_AS(&lds[sb][ldsB]), 16, 0, 0);
        }
        compute(cb);
        cb = (cb == 4) ? 0 : cb + 1;
    }
    // peeled tail: chunks 29 (buf 4), 30 (buf 0), 31 (buf 1)
    asm volatile("s_waitcnt vmcnt(4)" ::: "memory");
    __builtin_amdgcn_s_barrier();
    compute(4);
    asm volatile("s_waitcnt vmcnt(2)" ::: "memory");
    __builtin_amdgcn_s_barrier();
    compute(0);
    asm volatile("s_waitcnt vmcnt(0)" ::: "memory");
    __builtin_amdgcn_s_barrier();
    compute(1);

    // epilogue: exp(acc*10/64), diag-block triangle mask, row/col partials.
    // C layout (32x32): col = lane&31, row = (reg&3) + 8*(reg>>2) + 4*(lane>>5)
    __syncthreads();                         // K-loop fully done; lds reusable
    float* rpart = (float*)&lds[0][0];
    float* cpart = (float*)&lds[0][512];
    if (t < 128) { rpart[t] = 0.0f; cpart[t] = 0.0f; }
    __syncthreads();
    const int half = lane >> 5, col = lane & 31;
    float csum[2] = {0.0f, 0.0f};
    #pragma unroll
    for (int ti = 0; ti < 2; ++ti) {
        float rs[16];
        #pragma unroll
        for (int reg = 0; reg < 16; ++reg) rs[reg] = 0.0f;
        #pragma unroll
        for (int tj = 0; tj < 2; ++tj) {
            const int lj = qj * 64 + tj * 32 + col;
            #pragma unroll
            for (int reg = 0; reg < 16; ++reg) {
                const int li = qi * 64 + ti * 32 + (reg & 3) + 8 * (reg >> 2) + 4 * half;
                float e = __expf(acc[ti][tj][reg] * INVT_SCALED);
                if (diag && li >= lj) e = 0.0f;      // bi<bj blocks: always li<lj globally
                rs[reg] += e;
                csum[tj] += e;
            }
        }
        #pragma unroll
        for (int reg = 0; reg < 16; ++reg) {
            float v = rs[reg];
            v += __shfl_xor(v, 1); v += __shfl_xor(v, 2); v += __shfl_xor(v, 4);
            v += __shfl_xor(v, 8); v += __shfl_xor(v, 16);
            if (col == 0)
                atomicAdd(&rpart[qi * 64 + ti * 32 + (reg & 3) + 8 * (reg >> 2) + 4 * half], v);
        }
    }
    #pragma unroll
    for (int tj = 0; tj < 2; ++tj) {
        float v = csum[tj];
        v += __shfl_xor(v, 32);
        if (half == 0) atomicAdd(&cpart[qj * 64 + tj * 32 + col], v);
    }
    __syncthreads();
    if (t < 128) atomicAdd(&rowsum[bi * 128 + t], rpart[t]);
    else         atomicAdd(&rowsum[bj * 128 + (t - 128)], cpart[t - 128]);
}

// ---------------------------------------------------------------------------
// rowsum == sum_neg (diag + lower triangle excluded in gram)
__global__ __launch_bounds__(256) void final2_kernel(const float* __restrict__ rowsum,
                                                     float* __restrict__ out) {
    __shared__ float red[4];
    const int t = threadIdx.x;
    const int i = blockIdx.x * 256 + t;
    float v = logf(rowsum[i] * (1.0f / (float)(C - 1)));
    #pragma unroll
    for (int off = 32; off > 0; off >>= 1) v += __shfl_down(v, off);
    if ((t & 63) == 0) red[t >> 6] = v;
    __syncthreads();
    if (t == 0)
        atomicAdd(out, (red[0] + red[1] + red[2] + red[3]) * (1.0f / (float)C));
}

// ---------------------------------------------------------------------------
extern "C" void kernel_launch(void* const* d_in, const int* in_sizes, int n_in,
                              void* d_out, int out_size, void* d_ws, size_t ws_size,
                              hipStream_t stream) {
    const float* feat = (const float*)d_in[0];
    const int* labels = (const int*)d_in[1];
    const float* protos = (const float*)d_in[2];
    float* out = (float*)d_out;
    float* rowsum = (float*)d_ws;               // 32 KB
    u8* P8 = (u8*)((char*)d_ws + 32768);        // 8 MiB packed fp8 protos

    ema_split_kernel<<<C / 4, 256, 0, stream>>>(feat, labels, protos, P8, rowsum, out);
    gram8_kernel<<<2080, 256, 0, stream>>>(P8, rowsum);
    final2_kernel<<<C / 256, 256, 0, stream>>>(rowsum, out);
}

// Round 14
// 152.973 us; speedup vs baseline: 2.8268x; 1.0146x over previous
//
#include <hip/hip_runtime.h>
#include <math.h>

#define C 8192
#define D 1024
#define BATCH 1024
#define PM 0.95f
#define PMC 0.05f
// values pre-scaled by 8 before fp8 quant; dot comes out 64x too big.
// epilogue uses 10/64 = 0.15625 (exact in fp32).
#define INVT_SCALED 0.15625f

typedef unsigned char u8;
typedef __attribute__((ext_vector_type(16))) float f32x16;

#define GLOBAL_AS(p) ((const __attribute__((address_space(1))) void*)(p))
#define LDS_AS(p) ((__attribute__((address_space(3))) void*)(p))

// ---------------------------------------------------------------------------
// EMA + fp8 quantize, one wave per class (4 classes/block, 2048 blocks).
// Verified rounds 7-13. fp8 layout (512-B k-units for 32x32x16 fp8 MFMA):
//   element (row c, k) -> P8[(c>>5)*32768 + (k>>4)*512 + ((k>>3)&1)*256 + (c&31)*8 + (k&7)]
__global__ __launch_bounds__(256) void ema_split_kernel(const float* __restrict__ feat,
                                                        const int* __restrict__ labels,
                                                        const float* __restrict__ protos,
                                                        u8* __restrict__ P8,
                                                        float* __restrict__ rowsum,
                                                        float* __restrict__ out) {
    __shared__ int sl[BATCH];
    const int t = threadIdx.x, w = t >> 6, lane = t & 63;
    const int c = blockIdx.x * 4 + w;

    if (blockIdx.x < 32) rowsum[blockIdx.x * 256 + t] = 0.0f;
    if (blockIdx.x == 0 && t == 0) out[0] = 0.0f;

    for (int i = t; i < BATCH; i += 256) sl[i] = labels[i];
    __syncthreads();

    float4 v[4];
    #pragma unroll
    for (int s = 0; s < 4; ++s)
        v[s] = *(const float4*)(protos + (size_t)c * D + s * 256 + lane * 4);

    for (int base = 0; base < BATCH; base += 64) {
        unsigned long long mask = __ballot(sl[base + lane] == c);
        while (mask) {
            const int b = __ffsll((long long)mask) - 1;
            mask &= mask - 1;
            const int idx = base + b;
            float ss = 0.0f;
            #pragma unroll
            for (int s = 0; s < 4; ++s) {
                const float4 f = *(const float4*)(feat + (size_t)idx * D + s * 256 + lane * 4);
                v[s].x = v[s].x * PM + f.x * PMC;
                v[s].y = v[s].y * PM + f.y * PMC;
                v[s].z = v[s].z * PM + f.z * PMC;
                v[s].w = v[s].w * PM + f.w * PMC;
                ss += v[s].x * v[s].x + v[s].y * v[s].y + v[s].z * v[s].z + v[s].w * v[s].w;
            }
            #pragma unroll
            for (int off = 32; off > 0; off >>= 1) ss += __shfl_xor(ss, off);
            const float inv = 1.0f / fmaxf(sqrtf(ss), 1e-12f);
            #pragma unroll
            for (int s = 0; s < 4; ++s) {
                v[s].x *= inv; v[s].y *= inv; v[s].z *= inv; v[s].w *= inv;
            }
        }
    }

    u8* ob = P8 + (size_t)(c >> 5) * 32768 + (c & 31) * 8;
    #pragma unroll
    for (int s = 0; s < 4; ++s) {
        const int k0 = s * 256 + lane * 4;
        const size_t off = (size_t)(k0 >> 4) * 512 + ((k0 >> 3) & 1) * 256 + (k0 & 7);
        int p = __builtin_amdgcn_cvt_pk_fp8_f32(v[s].x * 8.0f, v[s].y * 8.0f, 0, false);
        p = __builtin_amdgcn_cvt_pk_fp8_f32(v[s].z * 8.0f, v[s].w * 8.0f, p, true);
        *(unsigned int*)(ob + off) = (unsigned int)p;
    }
}

// ---------------------------------------------------------------------------
// fp8 Gram, mfma_f32_32x32x16_fp8_fp8. r13 deep pipeline (5 LDS buffers,
// 40 KB, oldest-2 vmcnt waits, 4 blocks/CU) + NEW register-level fragment
// prefetch: two frag register sets; during MFMAs of K-step s, the ds_reads
// for step s+1 are already in flight (LDS latency hidden behind MFMA issue).
// Certification: vmcnt(4) at barrier kc certifies chunks kc AND kc+1 (oldest
// 4 of 8 outstanding), so prefetching chunk kc+1's first step during period
// kc is legal. WAR: buffer staged at period kc held chunk kc-1, last read
// (prefetch) pre-barrier-kc -> one full barrier separation.
// Triangle cover bi<=bj (2080 blocks); diag blocks mask li>=lj ->
// rowsum == sum_neg. XCD swizzle: 260 blocks/XCD.
__global__ __launch_bounds__(256, 4) void gram8_kernel(const u8* __restrict__ P8,
                                                       float* __restrict__ rowsum) {
    __shared__ u8 lds[5][8192];      // per buf: A tiles 0..3 @ a*1024, B @ 4096+
    const int t = threadIdx.x, w = t >> 6, lane = t & 63;

    // swizzled block -> (bi, bj), bi <= bj, 128-row strips
    int mm = blockIdx.x >> 3;
    const int r = blockIdx.x & 7;
    int bi = 0;
    #pragma unroll
    for (int s = 0; s < 8; ++s) {
        const int strip = (s & 1) ? ((s >> 1) * 16 + 15 - r) : ((s >> 1) * 16 + r);
        const int n = 64 - strip;
        if (mm < n) { bi = strip; break; }
        mm -= n;
    }
    const int bj = bi + mm;
    const bool diag = (bi == bj);

    // per-wave staging: 2 glds x 1 KB per chunk (A tile w, B tile w)
    const u8* gsrcA = P8 + (size_t)(bi * 4 + w) * 32768 + lane * 16;
    const u8* gsrcB = P8 + (size_t)(bj * 4 + w) * 32768 + lane * 16;
    const int ldsA = w * 1024, ldsB = 4096 + w * 1024;

    const int qi = w >> 1, qj = w & 1;
    const int aoff = qi * 2048 + lane * 8;          // A tile base within buf
    const int boff = 4096 + qj * 2048 + lane * 8;   // B tile base within buf

    f32x16 acc[2][2];
    #pragma unroll
    for (int a = 0; a < 2; ++a)
        #pragma unroll
        for (int b = 0; b < 2; ++b)
            #pragma unroll
            for (int e = 0; e < 16; ++e) acc[a][b][e] = 0.0f;

    long fa[2][2], fb[2][2];   // [reg set][tile]

#define STAGE(KC, BUF)                                                         \
    __builtin_amdgcn_global_load_lds(GLOBAL_AS(gsrcA + (size_t)(KC) * 1024),   \
                                     LDS_AS(&lds[BUF][ldsA]), 16, 0, 0);       \
    __builtin_amdgcn_global_load_lds(GLOBAL_AS(gsrcB + (size_t)(KC) * 1024),   \
                                     LDS_AS(&lds[BUF][ldsB]), 16, 0, 0);

#define PF(SET, BUF, KK)                                                       \
    fa[SET][0] = *(const long*)&lds[BUF][aoff + (KK) * 512];                   \
    fa[SET][1] = *(const long*)&lds[BUF][aoff + 1024 + (KK) * 512];            \
    fb[SET][0] = *(const long*)&lds[BUF][boff + (KK) * 512];                   \
    fb[SET][1] = *(const long*)&lds[BUF][boff + 1024 + (KK) * 512];

#define MFMA4(SET)                                                             \
    acc[0][0] = __builtin_amdgcn_mfma_f32_32x32x16_fp8_fp8(fa[SET][0], fb[SET][0], acc[0][0], 0, 0, 0); \
    acc[0][1] = __builtin_amdgcn_mfma_f32_32x32x16_fp8_fp8(fa[SET][0], fb[SET][1], acc[0][1], 0, 0, 0); \
    acc[1][0] = __builtin_amdgcn_mfma_f32_32x32x16_fp8_fp8(fa[SET][1], fb[SET][0], acc[1][0], 0, 0, 0); \
    acc[1][1] = __builtin_amdgcn_mfma_f32_32x32x16_fp8_fp8(fa[SET][1], fb[SET][1], acc[1][1], 0, 0, 0);

#define WAITV(N) asm volatile("s_waitcnt vmcnt(" #N ")" ::: "memory")

    // prologue: stage chunks 0..3 into bufs 0..3 (8 glds outstanding/wave)
    STAGE(0, 0); STAGE(1, 1); STAGE(2, 2); STAGE(3, 3);
    WAITV(4);                                // chunks 0,1 resident
    __builtin_amdgcn_s_barrier();
    PF(0, 0, 0);                             // step 0 (chunk 0, kk=0)

    int cb = 0;                              // buffer of chunk kc (kc % 5)
    for (int kc = 0; kc < 28; ++kc) {
        const int sb = (cb >= 1) ? cb - 1 : 4;       // (kc+4) % 5
        STAGE(kc + 4, sb);
        const int nb = (cb == 4) ? 0 : cb + 1;       // buffer of chunk kc+1
        PF(1, cb, 1);                        // step 2kc+1 (same chunk)
        MFMA4(0);                            // step 2kc
        PF(0, nb, 0);                        // step 2kc+2 (chunk kc+1 - certified)
        MFMA4(1);                            // step 2kc+1
        WAITV(4);                            // certifies chunks kc+1, kc+2
        __builtin_amdgcn_s_barrier();
        cb = nb;
    }
    // peeled tail (cb == 3): chunks 28..31 in bufs 3,4,0,1
    PF(1, 3, 1); MFMA4(0);                   // steps 56/57
    PF(0, 4, 0); MFMA4(1);
    WAITV(2); __builtin_amdgcn_s_barrier();  // certifies chunk 30
    PF(1, 4, 1); MFMA4(0);                   // steps 58/59
    PF(0, 0, 0); MFMA4(1);
    WAITV(0); __builtin_amdgcn_s_barrier();  // certifies chunk 31
    PF(1, 0, 1); MFMA4(0);                   // steps 60/61
    PF(0, 1, 0); MFMA4(1);
    PF(1, 1, 1); MFMA4(0);                   // steps 62/63
    MFMA4(1);

    // epilogue: exp(acc*10/64), diag-block triangle mask, row/col partials.
    // C layout (32x32): col = lane&31, row = (reg&3) + 8*(reg>>2) + 4*(lane>>5)
    __syncthreads();                         // K-loop fully done; lds reusable
    float* rpart = (float*)&lds[0][0];
    float* cpart = (float*)&lds[0][512];
    if (t < 128) { rpart[t] = 0.0f; cpart[t] = 0.0f; }
    __syncthreads();
    const int half = lane >> 5, col = lane & 31;
    float csum[2] = {0.0f, 0.0f};
    #pragma unroll
    for (int ti = 0; ti < 2; ++ti) {
        float rs[16];
        #pragma unroll
        for (int reg = 0; reg < 16; ++reg) rs[reg] = 0.0f;
        #pragma unroll
        for (int tj = 0; tj < 2; ++tj) {
            const int lj = qj * 64 + tj * 32 + col;
            #pragma unroll
            for (int reg = 0; reg < 16; ++reg) {
                const int li = qi * 64 + ti * 32 + (reg & 3) + 8 * (reg >> 2) + 4 * half;
                float e = __expf(acc[ti][tj][reg] * INVT_SCALED);
                if (diag && li >= lj) e = 0.0f;      // bi<bj blocks: always li<lj globally
                rs[reg] += e;
                csum[tj] += e;
            }
        }
        #pragma unroll
        for (int reg = 0; reg < 16; ++reg) {
            float v = rs[reg];
            v += __shfl_xor(v, 1); v += __shfl_xor(v, 2); v += __shfl_xor(v, 4);
            v += __shfl_xor(v, 8); v += __shfl_xor(v, 16);
            if (col == 0)
                atomicAdd(&rpart[qi * 64 + ti * 32 + (reg & 3) + 8 * (reg >> 2) + 4 * half], v);
        }
    }
    #pragma unroll
    for (int tj = 0; tj < 2; ++tj) {
        float v = csum[tj];
        v += __shfl_xor(v, 32);
        if (half == 0) atomicAdd(&cpart[qj * 64 + tj * 32 + col], v);
    }
    __syncthreads();
    if (t < 128) atomicAdd(&rowsum[bi * 128 + t], rpart[t]);
    else         atomicAdd(&rowsum[bj * 128 + (t - 128)], cpart[t - 128]);
}

// ---------------------------------------------------------------------------
// rowsum == sum_neg (diag + lower triangle excluded in gram)
__global__ __launch_bounds__(256) void final2_kernel(const float* __restrict__ rowsum,
                                                     float* __restrict__ out) {
    __shared__ float red[4];
    const int t = threadIdx.x;
    const int i = blockIdx.x * 256 + t;
    float v = logf(rowsum[i] * (1.0f / (float)(C - 1)));
    #pragma unroll
    for (int off = 32; off > 0; off >>= 1) v += __shfl_down(v, off);
    if ((t & 63) == 0) red[t >> 6] = v;
    __syncthreads();
    if (t == 0)
        atomicAdd(out, (red[0] + red[1] + red[2] + red[3]) * (1.0f / (float)C));
}

// ---------------------------------------------------------------------------
extern "C" void kernel_launch(void* const* d_in, const int* in_sizes, int n_in,
                              void* d_out, int out_size, void* d_ws, size_t ws_size,
                              hipStream_t stream) {
    const float* feat = (const float*)d_in[0];
    const int* labels = (const int*)d_in[1];
    const float* protos = (const float*)d_in[2];
    float* out = (float*)d_out;
    float* rowsum = (float*)d_ws;               // 32 KB
    u8* P8 = (u8*)((char*)d_ws + 32768);        // 8 MiB packed fp8 protos

    ema_split_kernel<<<C / 4, 256, 0, stream>>>(feat, labels, protos, P8, rowsum, out);
    gram8_kernel<<<2080, 256, 0, stream>>>(P8, rowsum);
    final2_kernel<<<C / 256, 256, 0, stream>>>(rowsum, out);
}